// Round 1
// baseline (280.567 us; speedup 1.0000x reference)
//
#include <hip/hip_runtime.h>
#include <stdint.h>

typedef __attribute__((ext_vector_type(8))) short short8;
typedef __attribute__((ext_vector_type(4))) float f32x4;

#define NEG_FLT_MAX (-3.402823466e38f)

__device__ __forceinline__ unsigned short f2bf(float f) {
  uint32_t u = __float_as_uint(f);
  uint32_t r = (u + 0x7fffu + ((u >> 16) & 1u)) >> 16;
  return (unsigned short)r;
}

__device__ __forceinline__ void gload16(const void* g, void* l) {
  __builtin_amdgcn_global_load_lds(
      (const __attribute__((address_space(1))) uint32_t*)g,
      (__attribute__((address_space(3))) uint32_t*)l, 16, 0, 0);
}

// ---------------- weight transpose + fp32->bf16 (+scale fold) ----------------
// src [R][C] f32 -> dst [C][R] bf16 * scale
__global__ void transpose_bf16_kernel(const float* __restrict__ src,
                                      unsigned short* __restrict__ dst,
                                      int R, int C, float scale) {
  __shared__ float tile[32][33];
  const int c0 = blockIdx.x * 32;
  const int r0 = blockIdx.y * 32;
  const int tx = threadIdx.x, ty = threadIdx.y;  // 32 x 8
#pragma unroll
  for (int i = ty; i < 32; i += 8)
    tile[i][tx] = src[(size_t)(r0 + i) * C + (c0 + tx)];
  __syncthreads();
#pragma unroll
  for (int i = ty; i < 32; i += 8)
    dst[(size_t)(c0 + i) * R + (r0 + tx)] = f2bf(tile[tx][i] * scale);
}

// ---------------- block reduction helper ----------------
__device__ __forceinline__ void block_reduce2(float& s, float& ss, float* red) {
#pragma unroll
  for (int off = 32; off > 0; off >>= 1) {
    s += __shfl_xor(s, off);
    ss += __shfl_xor(ss, off);
  }
  const int wave = threadIdx.x >> 6;
  const int lane = threadIdx.x & 63;
  if (lane == 0) { red[wave * 2] = s; red[wave * 2 + 1] = ss; }
  __syncthreads();
  if (threadIdx.x == 0) {
    float a = 0.f, b = 0.f;
    for (int i = 0; i < 4; i++) { a += red[i * 2]; b += red[i * 2 + 1]; }
    red[0] = a; red[1] = b;
  }
  __syncthreads();
  s = red[0]; ss = red[1];
}

// ---------------- LN vit: [18432][1024] f32 -> bf16 ----------------
__global__ __launch_bounds__(256) void ln_vit_kernel(
    const float* __restrict__ x, const float* __restrict__ w,
    const float* __restrict__ b, unsigned short* __restrict__ out) {
  __shared__ float red[8];
  const int row = blockIdx.x;
  const int t = threadIdx.x;
  const float4 v = ((const float4*)(x + (size_t)row * 1024))[t];
  float s = v.x + v.y + v.z + v.w;
  float ss = v.x * v.x + v.y * v.y + v.z * v.z + v.w * v.w;
  block_reduce2(s, ss, red);
  const float m = s * (1.f / 1024.f);
  const float var = ss * (1.f / 1024.f) - m * m;
  const float rstd = rsqrtf(var + 1e-5f);
  const float4 w4 = ((const float4*)w)[t];
  const float4 b4 = ((const float4*)b)[t];
  ushort4 o;
  o.x = f2bf((v.x - m) * rstd * w4.x + b4.x);
  o.y = f2bf((v.y - m) * rstd * w4.y + b4.y);
  o.z = f2bf((v.z - m) * rstd * w4.z + b4.z);
  o.w = f2bf((v.w - m) * rstd * w4.w + b4.w);
  ((ushort4*)(out + (size_t)row * 1024))[t] = o;
}

// ---------------- LN box: [3200][1536] f32 -> two bf16 outputs ----------------
__global__ __launch_bounds__(256) void ln_box_kernel(
    const float* __restrict__ x,
    const float* __restrict__ kw, const float* __restrict__ kb,
    const float* __restrict__ vw, const float* __restrict__ vb,
    unsigned short* __restrict__ kn, unsigned short* __restrict__ vn) {
  __shared__ float red[8];
  const int row = blockIdx.x;
  const int t = threadIdx.x;
  const float4* xr = (const float4*)(x + (size_t)row * 1536);
  const float4 a = xr[t];
  float4 c = make_float4(0.f, 0.f, 0.f, 0.f);
  if (t < 128) c = xr[256 + t];
  float s = a.x + a.y + a.z + a.w + c.x + c.y + c.z + c.w;
  float ss = a.x * a.x + a.y * a.y + a.z * a.z + a.w * a.w +
             c.x * c.x + c.y * c.y + c.z * c.z + c.w * c.w;
  block_reduce2(s, ss, red);
  const float m = s * (1.f / 1536.f);
  const float var = ss * (1.f / 1536.f) - m * m;
  const float rstd = rsqrtf(var + 1e-5f);
  {
    const float4 w4 = ((const float4*)kw)[t];
    const float4 b4 = ((const float4*)kb)[t];
    ushort4 o;
    o.x = f2bf((a.x - m) * rstd * w4.x + b4.x);
    o.y = f2bf((a.y - m) * rstd * w4.y + b4.y);
    o.z = f2bf((a.z - m) * rstd * w4.z + b4.z);
    o.w = f2bf((a.w - m) * rstd * w4.w + b4.w);
    ((ushort4*)(kn + (size_t)row * 1536))[t] = o;
    const float4 w4v = ((const float4*)vw)[t];
    const float4 b4v = ((const float4*)vb)[t];
    o.x = f2bf((a.x - m) * rstd * w4v.x + b4v.x);
    o.y = f2bf((a.y - m) * rstd * w4v.y + b4v.y);
    o.z = f2bf((a.z - m) * rstd * w4v.z + b4v.z);
    o.w = f2bf((a.w - m) * rstd * w4v.w + b4v.w);
    ((ushort4*)(vn + (size_t)row * 1536))[t] = o;
  }
  if (t < 128) {
    const int t2 = 256 + t;
    const float4 w4 = ((const float4*)kw)[t2];
    const float4 b4 = ((const float4*)kb)[t2];
    ushort4 o;
    o.x = f2bf((c.x - m) * rstd * w4.x + b4.x);
    o.y = f2bf((c.y - m) * rstd * w4.y + b4.y);
    o.z = f2bf((c.z - m) * rstd * w4.z + b4.z);
    o.w = f2bf((c.w - m) * rstd * w4.w + b4.w);
    ((ushort4*)(kn + (size_t)row * 1536))[t2] = o;
    const float4 w4v = ((const float4*)vw)[t2];
    const float4 b4v = ((const float4*)vb)[t2];
    o.x = f2bf((c.x - m) * rstd * w4v.x + b4v.x);
    o.y = f2bf((c.y - m) * rstd * w4v.y + b4v.y);
    o.z = f2bf((c.z - m) * rstd * w4v.z + b4v.z);
    o.w = f2bf((c.w - m) * rstd * w4v.w + b4v.w);
    ((ushort4*)(vn + (size_t)row * 1536))[t2] = o;
  }
}

// ---------------- GEMM core: C_tile = A[M,K] * Bt[N,K]^T, 128x128 tile ----------------
// 256 threads = 4 waves (2x2), each wave 64x64 via 4x4 of 16x16x32 MFMA frags.
__device__ __forceinline__ void gemm_core(
    const unsigned short* __restrict__ A, int lda, int rowmaxA, int tm0,
    const unsigned short* __restrict__ Bt, int ldb, int rowmaxB, int tn0,
    int K, unsigned short* As, unsigned short* Bs, f32x4 acc[4][4]) {
  const int tid = threadIdx.x;
  const int w = tid >> 6, l = tid & 63;
  const int wr = w >> 1, wc = w & 1;
  const int srow = (w << 4) + (l >> 2);
  const int scol = (l & 3) << 3;
  int ra0 = tm0 + srow;      if (ra0 > rowmaxA) ra0 = rowmaxA;
  int ra1 = tm0 + srow + 64; if (ra1 > rowmaxA) ra1 = rowmaxA;
  int rb0 = tn0 + srow;      if (rb0 > rowmaxB) rb0 = rowmaxB;
  int rb1 = tn0 + srow + 64; if (rb1 > rowmaxB) rb1 = rowmaxB;
  const unsigned short* pa0 = A + (size_t)ra0 * lda + scol;
  const unsigned short* pa1 = A + (size_t)ra1 * lda + scol;
  const unsigned short* pb0 = Bt + (size_t)rb0 * ldb + scol;
  const unsigned short* pb1 = Bt + (size_t)rb1 * ldb + scol;
  unsigned short* la0 = As + (w << 4) * 32;
  unsigned short* la1 = As + ((w << 4) + 64) * 32;
  unsigned short* lb0 = Bs + (w << 4) * 32;
  unsigned short* lb1 = Bs + ((w << 4) + 64) * 32;
  const int foff = ((l & 15) << 5) + ((l >> 4) << 3);
  const unsigned short* fa = As + (wr << 6) * 32 + foff;
  const unsigned short* fb = Bs + (wc << 6) * 32 + foff;
#pragma unroll
  for (int i = 0; i < 4; i++)
#pragma unroll
    for (int j = 0; j < 4; j++) acc[i][j] = (f32x4)0.0f;
  for (int k0 = 0; k0 < K; k0 += 32) {
    gload16(pa0 + k0, la0);
    gload16(pa1 + k0, la1);
    gload16(pb0 + k0, lb0);
    gload16(pb1 + k0, lb1);
    __syncthreads();
    short8 a[4], b[4];
#pragma unroll
    for (int i = 0; i < 4; i++) a[i] = *(const short8*)(fa + i * 16 * 32);
#pragma unroll
    for (int j = 0; j < 4; j++) b[j] = *(const short8*)(fb + j * 16 * 32);
#pragma unroll
    for (int i = 0; i < 4; i++)
#pragma unroll
      for (int j = 0; j < 4; j++)
        acc[i][j] = __builtin_amdgcn_mfma_f32_16x16x32_bf16(a[i], b[j], acc[i][j], 0, 0, 0);
    __syncthreads();
  }
}

// ---------------- QKV projection GEMM: bf16 out (+bias), optional transposed V write ----
__global__ __launch_bounds__(256) void gemm_qkv_kernel(
    const unsigned short* __restrict__ A, const unsigned short* __restrict__ Bt,
    const float* __restrict__ bias, float bscale,
    unsigned short* __restrict__ C, int M, int N, int K,
    int trans, int rpb, int tld) {
  __shared__ unsigned short As[128 * 32];
  __shared__ unsigned short Bs[128 * 32];
  const int tm0 = blockIdx.x * 128, tn0 = blockIdx.y * 128;
  f32x4 acc[4][4];
  gemm_core(A, K, M - 1, tm0, Bt, K, N - 1, tn0, K, As, Bs, acc);
  const int tid = threadIdx.x;
  const int w = tid >> 6, l = tid & 63;
  const int wr = w >> 1, wc = w & 1;
#pragma unroll
  for (int i = 0; i < 4; i++) {
    const int row0 = tm0 + wr * 64 + i * 16 + (l >> 4) * 4;
#pragma unroll
    for (int j = 0; j < 4; j++) {
      const int col = tn0 + wc * 64 + j * 16 + (l & 15);
      const float bv = bias[col] * bscale;
#pragma unroll
      for (int r = 0; r < 4; r++) {
        const int row = row0 + r;
        const float val = acc[i][j][r] + bv;
        if (!trans) {
          C[(size_t)row * N + col] = f2bf(val);
        } else {
          const int bb = row / rpb;
          const int ll = row - bb * rpb;
          C[((size_t)bb * N + col) * tld + ll] = f2bf(val);
        }
      }
    }
  }
}

// ---------------- ATT1: logits = q.k^T (scale prefolded), mask, softmax -> bf16 att ----
__global__ __launch_bounds__(256) void att1_kernel(
    const unsigned short* __restrict__ q, const unsigned short* __restrict__ k,
    const int* __restrict__ lengths, unsigned short* __restrict__ att) {
  __shared__ __align__(16) char smem[104 * 132 * 4];
  unsigned short* As = (unsigned short*)smem;
  unsigned short* Bs = As + 128 * 32;
  float* Smat = (float*)smem;  // [104][132] col-major-ish: Smat[c*132 + row]
  const int b = blockIdx.y;
  const int tm0 = blockIdx.x * 128;
  f32x4 acc[4][4];
  gemm_core(q + (size_t)b * 576 * 1024, 1024, 575, tm0,
            k + (size_t)b * 100 * 1024, 1024, 99, 0, 1024, As, Bs, acc);
  __syncthreads();
  const int tid = threadIdx.x;
  const int w = tid >> 6, l = tid & 63;
  const int wr = w >> 1, wc = w & 1;
#pragma unroll
  for (int i = 0; i < 4; i++) {
#pragma unroll
    for (int j = 0; j < 4; j++) {
      const int c = wc * 64 + j * 16 + (l & 15);
      if (c < 104) {
        const int lr0 = wr * 64 + i * 16 + (l >> 4) * 4;
#pragma unroll
        for (int r = 0; r < 4; r++) Smat[(size_t)c * 132 + lr0 + r] = acc[i][j][r];
      }
    }
  }
  __syncthreads();
  const int t = tid;
  if (t < 128) {
    const int row = tm0 + t;
    if (row < 576) {
      const int len = lengths[b];
      float mx = NEG_FLT_MAX;
      for (int ll = 0; ll < 100; ll++) {
        const float v = (ll < len) ? Smat[ll * 132 + t] : NEG_FLT_MAX;
        mx = fmaxf(mx, v);
      }
      float sum = 0.f;
      for (int ll = 0; ll < 100; ll++) {
        const float v = (ll < len) ? Smat[ll * 132 + t] : NEG_FLT_MAX;
        const float e = __expf(v - mx);
        Smat[ll * 132 + t] = e;
        sum += e;
      }
      const float inv = 1.f / sum;
      unsigned short* arow = att + ((size_t)b * 576 + row) * 128;
      for (int ll = 0; ll < 100; ll++) arow[ll] = f2bf(Smat[ll * 132 + t] * inv);
      for (int ll = 100; ll < 128; ll++) arow[ll] = 0;
    }
  }
}

// ---------------- ATT2: out = att @ v + vit (fp32 out) ----------------
__global__ __launch_bounds__(256) void att2_kernel(
    const unsigned short* __restrict__ att, const unsigned short* __restrict__ vT,
    const float* __restrict__ vit, float* __restrict__ out) {
  __shared__ unsigned short As[128 * 32];
  __shared__ unsigned short Bs[128 * 32];
  const int b = blockIdx.z;
  const int tm0 = blockIdx.x * 128, tn0 = blockIdx.y * 128;
  f32x4 acc[4][4];
  gemm_core(att + (size_t)b * 576 * 128, 128, 575, tm0,
            vT + (size_t)b * 1024 * 128, 128, 1023, tn0, 128, As, Bs, acc);
  const int tid = threadIdx.x;
  const int w = tid >> 6, l = tid & 63;
  const int wr = w >> 1, wc = w & 1;
#pragma unroll
  for (int i = 0; i < 4; i++) {
    const int row0 = tm0 + wr * 64 + i * 16 + (l >> 4) * 4;
#pragma unroll
    for (int j = 0; j < 4; j++) {
      const int col = tn0 + wc * 64 + j * 16 + (l & 15);
#pragma unroll
      for (int r = 0; r < 4; r++) {
        const int row = row0 + r;
        if (row < 576) {
          const size_t idx = ((size_t)b * 576 + row) * 1024 + col;
          out[idx] = acc[i][j][r] + vit[idx];
        }
      }
    }
  }
}

extern "C" void kernel_launch(void* const* d_in, const int* in_sizes, int n_in,
                              void* d_out, int out_size, void* d_ws, size_t ws_size,
                              hipStream_t stream) {
  const float* vit = (const float*)d_in[0];
  const float* box = (const float*)d_in[1];
  const int* lengths = (const int*)d_in[2];
  const float* q_ln_w = (const float*)d_in[3];
  const float* q_ln_b = (const float*)d_in[4];
  const float* q_w = (const float*)d_in[5];
  const float* q_b = (const float*)d_in[6];
  const float* k_ln_w = (const float*)d_in[7];
  const float* k_ln_b = (const float*)d_in[8];
  const float* k_w = (const float*)d_in[9];
  const float* k_b = (const float*)d_in[10];
  const float* v_ln_w = (const float*)d_in[11];
  const float* v_ln_b = (const float*)d_in[12];
  const float* v_w = (const float*)d_in[13];
  const float* v_b = (const float*)d_in[14];
  float* out = (float*)d_out;
  char* ws = (char*)d_ws;

  // ws layout (bytes); q overlaps kn/vn which are dead before q is written
  unsigned short* q    = (unsigned short*)(ws + 0);          // [18432][1024] bf16 (37,748,736 B)
  unsigned short* kn   = (unsigned short*)(ws + 0);          // [3200][1536]
  unsigned short* vn   = (unsigned short*)(ws + 9830400);    // [3200][1536]
  unsigned short* k_wt = (unsigned short*)(ws + 37748736);   // [1024][1536]
  unsigned short* v_wt = (unsigned short*)(ws + 40894464);   // [1024][1536]
  unsigned short* q_wt = (unsigned short*)(ws + 44040192);   // [1024][1024]
  unsigned short* kk   = (unsigned short*)(ws + 46137344);   // [3200][1024]
  unsigned short* vT   = (unsigned short*)(ws + 52690944);   // [32][1024][128]
  unsigned short* att  = (unsigned short*)(ws + 61079552);   // [32][576][128]
  unsigned short* qn   = (unsigned short*)d_out;             // bf16 scratch inside output buf

  const float scale = 0.03125f;  // 1/sqrt(1024)
  dim3 tb(32, 8);

  // 1. weights: transpose + convert (+fold scale into k)
  transpose_bf16_kernel<<<dim3(32, 32), tb, 0, stream>>>(q_w, q_wt, 1024, 1024, 1.0f);
  transpose_bf16_kernel<<<dim3(32, 48), tb, 0, stream>>>(k_w, k_wt, 1536, 1024, scale);
  transpose_bf16_kernel<<<dim3(32, 48), tb, 0, stream>>>(v_w, v_wt, 1536, 1024, 1.0f);

  // 2. LN box (shared stats, two outputs)
  ln_box_kernel<<<3200, 256, 0, stream>>>(box, k_ln_w, k_ln_b, v_ln_w, v_ln_b, kn, vn);

  // 3. K and V projections (V written transposed into [B][1024][128], l-padded)
  gemm_qkv_kernel<<<dim3(25, 8), 256, 0, stream>>>(kn, k_wt, k_b, scale, kk, 3200, 1024, 1536, 0, 0, 0);
  gemm_qkv_kernel<<<dim3(25, 8), 256, 0, stream>>>(vn, v_wt, v_b, 1.0f, vT, 3200, 1024, 1536, 1, 100, 128);

  // 4. LN vit -> qn (scratch in d_out)
  ln_vit_kernel<<<18432, 256, 0, stream>>>(vit, q_ln_w, q_ln_b, qn);

  // 5. Q projection (overwrites kn/vn region — they are dead)
  gemm_qkv_kernel<<<dim3(144, 8), 256, 0, stream>>>(qn, q_wt, q_b, 1.0f, q, 18432, 1024, 1024, 0, 0, 0);

  // 6. attention scores + masked softmax -> bf16 att [B][576][128] (cols>=100 zeroed)
  att1_kernel<<<dim3(5, 32), 256, 0, stream>>>(q, kk, lengths, att);

  // 7. out = att @ v + vit
  att2_kernel<<<dim3(5, 8, 32), 256, 0, stream>>>(att, vT, vit, out);

  (void)in_sizes; (void)n_in; (void)out_size; (void)ws_size;
}